// Round 2
// baseline (430.427 us; speedup 1.0000x reference)
//
#include <hip/hip_runtime.h>
#include <hip/hip_bf16.h>

typedef unsigned short u16;
typedef __bf16 bf16x8 __attribute__((ext_vector_type(8)));
typedef float f32x4 __attribute__((ext_vector_type(4)));

#define MDIM 16384   // 8 * 2048 rows of x
#define NDIM 2048    // output features
#define KDIM 2048    // input features
#define RANK 16
#define BM 128
#define BN 128
#define BK 64        // two 16x16x32 MFMA K-steps per barrier (was 32)

#define WPREP_BLOCKS (NDIM * (KDIM / 4) / 256)          // 4096
#define XCONV_BLOCKS (MDIM * (KDIM / 4) / 256)          // 32768

// ---- fp32 -> bf16 round-to-nearest-even ----
__device__ __forceinline__ u16 f2bf(float f) {
    union { float f; unsigned u; } v; v.f = f;
    unsigned u = v.u;
    u += 0x7FFFu + ((u >> 16) & 1u);   // RNE
    return (u16)(u >> 16);
}

// ---- async global->LDS, 16B/lane, dest = wave-uniform base + lane*16 ----
__device__ __forceinline__ void async_copy16(const void* gsrc, void* ldst) {
    __builtin_amdgcn_global_load_lds(
        (const __attribute__((address_space(1))) void*)gsrc,
        (__attribute__((address_space(3))) void*)ldst,
        16, 0, 0);
}

// ============================================================
// Kernel 1 (fused): first WPREP_BLOCKS blocks build w = W + 2*B@A -> bf16,
// remaining blocks convert x fp32 -> bf16. Branch is block-uniform.
// ============================================================
__global__ __launch_bounds__(256) void prep(const float* __restrict__ x,
                                            const float* __restrict__ W,
                                            const float* __restrict__ Bm,
                                            const float* __restrict__ Am,
                                            u16* __restrict__ xb,
                                            u16* __restrict__ wb) {
    const int bid = blockIdx.x;
    if (bid < WPREP_BLOCKS) {
        int t  = bid * 256 + threadIdx.x;   // 0 .. NDIM*(KDIM/4)-1
        int o  = t >> 9;                    // / (KDIM/4)
        int dq = t & 511;                   // float4 index within row
        float4 acc = ((const float4*)W)[(size_t)o * (KDIM / 4) + dq];
        const float* Bo = Bm + (size_t)o * RANK;
#pragma unroll
        for (int r = 0; r < RANK; ++r) {
            float bv = 2.0f * Bo[r];        // ALPHA/RANK = 2
            float4 a4 = ((const float4*)(Am + (size_t)r * KDIM))[dq];
            acc.x += bv * a4.x; acc.y += bv * a4.y;
            acc.z += bv * a4.z; acc.w += bv * a4.w;
        }
        ushort4 ov;
        ov.x = f2bf(acc.x); ov.y = f2bf(acc.y);
        ov.z = f2bf(acc.z); ov.w = f2bf(acc.w);
        ((ushort4*)wb)[t] = ov;
    } else {
        int t = (bid - WPREP_BLOCKS) * 256 + threadIdx.x;  // 0 .. MDIM*KDIM/4-1
        float4 v = ((const float4*)x)[t];
        ushort4 o;
        o.x = f2bf(v.x); o.y = f2bf(v.y); o.z = f2bf(v.z); o.w = f2bf(v.w);
        ((ushort4*)xb)[t] = o;
    }
}

// ============================================================
// Kernel 2: C[m,n] = sum_k xb[m,k]*wb[n,k] + bias[n]   (bf16 MFMA, fp32 out)
// m97 structure, BK=64: per iter 8 global_load_lds(16B)/wave, 1 barrier-drain,
// 16 ds_read_b128, 32 MFMA -> 16 MFMA per barrier (was 8).
// ============================================================
__global__ __launch_bounds__(256) void gemm_bt(const u16* __restrict__ xb,
                                               const u16* __restrict__ wb,
                                               const float* __restrict__ bias,
                                               float* __restrict__ out) {
    __shared__ __align__(16) u16 As[BM * BK];   // [row][k], 128B rows, 16 KB
    __shared__ __align__(16) u16 Bs[BN * BK];   // 16 KB

    const int tid  = threadIdx.x;
    const int lane = tid & 63;
    const int w    = tid >> 6;          // wave 0..3
    const int m0   = blockIdx.y * BM;
    const int n0   = blockIdx.x * BN;

    // staging: one wave-issue = 64 lanes * 16B = 1024B = 8 rows of 128B
    const int srow  = lane >> 3;        // row within 8-row chunk
    const int selem = (lane & 7) * 8;   // bf16 offset within row (8 bf16 = 16B)

    // wave sub-tile: 2x2 waves, each 64x64
    const int wr   = (w >> 1) * 64;
    const int wc   = (w & 1) * 64;
    const int quad = lane >> 4;
    const int l16  = lane & 15;

    int a_off[4], b_off[4];
#pragma unroll
    for (int i = 0; i < 4; ++i) {
        a_off[i] = (wr + i * 16 + l16) * BK + quad * 8;
        b_off[i] = (wc + i * 16 + l16) * BK + quad * 8;
    }

    f32x4 acc[4][4];
#pragma unroll
    for (int i = 0; i < 4; ++i)
#pragma unroll
        for (int j = 0; j < 4; ++j)
            acc[i][j] = (f32x4){0.f, 0.f, 0.f, 0.f};

    const u16* ga = xb + (size_t)m0 * KDIM;
    const u16* gb = wb + (size_t)n0 * KDIM;

    for (int k0 = 0; k0 < KDIM; k0 += BK) {
        // stage: wave w fills rows [w*32, w*32+32) of both tiles, 4 chunks of 8 rows
#pragma unroll
        for (int c = 0; c < 4; ++c) {
            const int rbase = w * 32 + c * 8;
            async_copy16(ga + (size_t)(rbase + srow) * KDIM + k0 + selem,
                         (char*)As + (size_t)rbase * (BK * 2));
            async_copy16(gb + (size_t)(rbase + srow) * KDIM + k0 + selem,
                         (char*)Bs + (size_t)rbase * (BK * 2));
        }
        __syncthreads();   // vmcnt(0) drain + barrier (32 total, was 64)

#pragma unroll
        for (int s = 0; s < 2; ++s) {      // two K-steps of 32 within the stage
            bf16x8 af[4], bfr[4];
#pragma unroll
            for (int i = 0; i < 4; ++i) af[i]  = *(const bf16x8*)(As + a_off[i] + s * 32);
#pragma unroll
            for (int j = 0; j < 4; ++j) bfr[j] = *(const bf16x8*)(Bs + b_off[j] + s * 32);

#pragma unroll
            for (int i = 0; i < 4; ++i)
#pragma unroll
                for (int j = 0; j < 4; ++j)
                    acc[i][j] = __builtin_amdgcn_mfma_f32_16x16x32_bf16(
                        af[i], bfr[j], acc[i][j], 0, 0, 0);
        }

        __syncthreads();   // protect LDS reuse next iteration
    }

    // epilogue: C/D layout col=lane&15, row=quad*4+reg  [m89/m91 verified]
#pragma unroll
    for (int j = 0; j < 4; ++j) {
        const int col = n0 + wc + j * 16 + l16;
        const float bj = bias[col];
#pragma unroll
        for (int i = 0; i < 4; ++i) {
            const int rowb = m0 + wr + i * 16 + quad * 4;
#pragma unroll
            for (int r = 0; r < 4; ++r)
                out[(size_t)(rowb + r) * NDIM + col] = acc[i][j][r] + bj;
        }
    }
}

extern "C" void kernel_launch(void* const* d_in, const int* in_sizes, int n_in,
                              void* d_out, int out_size, void* d_ws, size_t ws_size,
                              hipStream_t stream) {
    const float* x    = (const float*)d_in[0];   // [8,2048,2048]
    const float* W    = (const float*)d_in[1];   // [2048,2048] row-major [o,d]
    const float* bias = (const float*)d_in[2];   // [2048]
    const float* Bm   = (const float*)d_in[3];   // [2048,16]
    const float* Am   = (const float*)d_in[4];   // [16,2048]
    float* out = (float*)d_out;

    u16* xb   = (u16*)d_ws;                      // 16384*2048 bf16 = 64 MB
    u16* wbuf = xb + (size_t)MDIM * KDIM;        // 2048*2048 bf16 = 8 MB

    prep<<<WPREP_BLOCKS + XCONV_BLOCKS, 256, 0, stream>>>(x, W, Bm, Am, xb, wbuf);

    dim3 grid(NDIM / BN, MDIM / BM);   // (16, 128)
    gemm_bt<<<grid, 256, 0, stream>>>(xb, wbuf, bias, out);
}

// Round 3
// 403.497 us; speedup vs baseline: 1.0667x; 1.0667x over previous
//
#include <hip/hip_runtime.h>
#include <hip/hip_bf16.h>

typedef unsigned short u16;
typedef __bf16 bf16x8 __attribute__((ext_vector_type(8)));
typedef float f32x4 __attribute__((ext_vector_type(4)));

#define MDIM 16384   // 8 * 2048 rows of x
#define NDIM 2048    // output features
#define KDIM 2048    // input features
#define RANK 16
#define BM 128
#define BN 128
#define BK 64        // two 16x16x32 MFMA K-steps per barrier

#define WPREP_BLOCKS (NDIM * (KDIM / 4) / 256)          // 4096
#define XCONV_BLOCKS (MDIM * (KDIM / 4) / 256)          // 32768

// ---- fp32 -> bf16 round-to-nearest-even ----
__device__ __forceinline__ u16 f2bf(float f) {
    union { float f; unsigned u; } v; v.f = f;
    unsigned u = v.u;
    u += 0x7FFFu + ((u >> 16) & 1u);   // RNE
    return (u16)(u >> 16);
}

// ---- async global->LDS, 16B/lane, dest = wave-uniform base + lane*16 ----
__device__ __forceinline__ void async_copy16(const void* gsrc, void* ldst) {
    __builtin_amdgcn_global_load_lds(
        (const __attribute__((address_space(1))) void*)gsrc,
        (__attribute__((address_space(3))) void*)ldst,
        16, 0, 0);
}

// ============================================================
// Kernel 1 (fused): first WPREP_BLOCKS blocks build w = W + 2*B@A -> bf16,
// remaining blocks convert x fp32 -> bf16. Branch is block-uniform.
// ============================================================
__global__ __launch_bounds__(256) void prep(const float* __restrict__ x,
                                            const float* __restrict__ W,
                                            const float* __restrict__ Bm,
                                            const float* __restrict__ Am,
                                            u16* __restrict__ xb,
                                            u16* __restrict__ wb) {
    const int bid = blockIdx.x;
    if (bid < WPREP_BLOCKS) {
        int t  = bid * 256 + threadIdx.x;   // 0 .. NDIM*(KDIM/4)-1
        int o  = t >> 9;                    // / (KDIM/4)
        int dq = t & 511;                   // float4 index within row
        float4 acc = ((const float4*)W)[(size_t)o * (KDIM / 4) + dq];
        const float* Bo = Bm + (size_t)o * RANK;
#pragma unroll
        for (int r = 0; r < RANK; ++r) {
            float bv = 2.0f * Bo[r];        // ALPHA/RANK = 2
            float4 a4 = ((const float4*)(Am + (size_t)r * KDIM))[dq];
            acc.x += bv * a4.x; acc.y += bv * a4.y;
            acc.z += bv * a4.z; acc.w += bv * a4.w;
        }
        ushort4 ov;
        ov.x = f2bf(acc.x); ov.y = f2bf(acc.y);
        ov.z = f2bf(acc.z); ov.w = f2bf(acc.w);
        ((ushort4*)wb)[t] = ov;
    } else {
        int t = (bid - WPREP_BLOCKS) * 256 + threadIdx.x;  // 0 .. MDIM*KDIM/4-1
        float4 v = ((const float4*)x)[t];
        ushort4 o;
        o.x = f2bf(v.x); o.y = f2bf(v.y); o.z = f2bf(v.z); o.w = f2bf(v.w);
        ((ushort4*)xb)[t] = o;
    }
}

// ============================================================
// Kernel 2: C[m,n] = sum_k xb[m,k]*wb[n,k] + bias[n]   (bf16 MFMA, fp32 out)
// BK=64 + XOR-swizzled LDS: row r (128 B = 8 chunks of 16 B) stores global
// chunk c at slot c^(r&7). Staging lane fetches permuted chunk so the
// wave-uniform global_load_lds dest stays legal; reads XOR the slot back.
// Bank group of a fragment read = (((s*4+quad)^(l16&7))&7)*4 -> all 8 groups
// covered across l16 -> 2 lanes/bank = conflict-free (m136).
// ============================================================
__global__ __launch_bounds__(256) void gemm_bt(const u16* __restrict__ xb,
                                               const u16* __restrict__ wb,
                                               const float* __restrict__ bias,
                                               float* __restrict__ out) {
    __shared__ __align__(16) u16 As[BM * BK];   // 16 KB, rows = 128 B
    __shared__ __align__(16) u16 Bs[BN * BK];   // 16 KB

    const int tid  = threadIdx.x;
    const int lane = tid & 63;
    const int w    = tid >> 6;          // wave 0..3
    const int m0   = blockIdx.y * BM;
    const int n0   = blockIdx.x * BN;

    // staging: one wave-issue = 64 lanes * 16 B = 1024 B = 8 rows of 128 B
    const int srow   = lane >> 3;                    // row within 8-row chunk
    const int schunk = (lane & 7) ^ srow;            // permuted global chunk
    const int selem  = schunk * 8;                   // bf16 offset within row

    // wave sub-tile: 2x2 waves, each 64x64
    const int wr   = (w >> 1) * 64;
    const int wc   = (w & 1) * 64;
    const int quad = lane >> 4;
    const int l16  = lane & 15;
    const int swz  = l16 & 7;

    int a_row[4], b_row[4];
#pragma unroll
    for (int i = 0; i < 4; ++i) {
        a_row[i] = (wr + i * 16 + l16) * BK;
        b_row[i] = (wc + i * 16 + l16) * BK;
    }

    f32x4 acc[4][4];
#pragma unroll
    for (int i = 0; i < 4; ++i)
#pragma unroll
        for (int j = 0; j < 4; ++j)
            acc[i][j] = (f32x4){0.f, 0.f, 0.f, 0.f};

    const u16* ga = xb + (size_t)m0 * KDIM;
    const u16* gb = wb + (size_t)n0 * KDIM;

    for (int k0 = 0; k0 < KDIM; k0 += BK) {
        // stage: wave w fills rows [w*32, w*32+32), 4 chunks of 8 rows
#pragma unroll
        for (int c = 0; c < 4; ++c) {
            const int rbase = w * 32 + c * 8;
            async_copy16(ga + (size_t)(rbase + srow) * KDIM + k0 + selem,
                         (char*)As + (size_t)rbase * (BK * 2));
            async_copy16(gb + (size_t)(rbase + srow) * KDIM + k0 + selem,
                         (char*)Bs + (size_t)rbase * (BK * 2));
        }
        __syncthreads();   // vmcnt(0) drain + barrier (32 total)

#pragma unroll
        for (int s = 0; s < 2; ++s) {      // two K-steps of 32
            bf16x8 af[4], bfr[4];
#pragma unroll
            for (int i = 0; i < 4; ++i)
                af[i]  = *(const bf16x8*)(As + a_row[i] + (((s * 4 + quad) ^ swz) << 3));
#pragma unroll
            for (int j = 0; j < 4; ++j)
                bfr[j] = *(const bf16x8*)(Bs + b_row[j] + (((s * 4 + quad) ^ swz) << 3));

#pragma unroll
            for (int i = 0; i < 4; ++i)
#pragma unroll
                for (int j = 0; j < 4; ++j)
                    acc[i][j] = __builtin_amdgcn_mfma_f32_16x16x32_bf16(
                        af[i], bfr[j], acc[i][j], 0, 0, 0);
        }

        __syncthreads();   // protect LDS reuse next iteration
    }

    // epilogue: C/D layout col=lane&15, row=quad*4+reg  [m89/m91 verified]
#pragma unroll
    for (int j = 0; j < 4; ++j) {
        const int col = n0 + wc + j * 16 + l16;
        const float bj = bias[col];
#pragma unroll
        for (int i = 0; i < 4; ++i) {
            const int rowb = m0 + wr + i * 16 + quad * 4;
#pragma unroll
            for (int r = 0; r < 4; ++r)
                out[(size_t)(rowb + r) * NDIM + col] = acc[i][j][r] + bj;
        }
    }
}

extern "C" void kernel_launch(void* const* d_in, const int* in_sizes, int n_in,
                              void* d_out, int out_size, void* d_ws, size_t ws_size,
                              hipStream_t stream) {
    const float* x    = (const float*)d_in[0];   // [8,2048,2048]
    const float* W    = (const float*)d_in[1];   // [2048,2048] row-major [o,d]
    const float* bias = (const float*)d_in[2];   // [2048]
    const float* Bm   = (const float*)d_in[3];   // [2048,16]
    const float* Am   = (const float*)d_in[4];   // [16,2048]
    float* out = (float*)d_out;

    u16* xb   = (u16*)d_ws;                      // 16384*2048 bf16 = 64 MB
    u16* wbuf = xb + (size_t)MDIM * KDIM;        // 2048*2048 bf16 = 8 MB

    prep<<<WPREP_BLOCKS + XCONV_BLOCKS, 256, 0, stream>>>(x, W, Bm, Am, xb, wbuf);

    dim3 grid(NDIM / BN, MDIM / BM);   // (16, 128)
    gemm_bt<<<grid, 256, 0, stream>>>(xb, wbuf, bias, out);
}